// Round 8
// baseline (70.155 us; speedup 1.0000x reference)
//
#include <hip/hip_runtime.h>
#include <hip/hip_bf16.h>
#include <math.h>

// TokenCompressor: B=8, N=16384, C=128, BLOCK=32, STRIDE=16 -> nb=1023
// Decomposition: chunks c of 16 tokens; A = x.view(8192, 2048) (contiguous!)
//   P[m, 0:256]  = chunk[m] @ W1[0:2048]
//   P[m, 256:512]= chunk[m] @ W1[2048:4096]
//   h[j] = gelu(P[j,0:256] + P[j+1,256:512] + b1 + posflat@W1)
//   out[j] = h[j] @ W2 + b2
// R8: m201-class chassis for k_gemm. R2-R7 all ~12% MfmaUtil: with <=3
// waves/SIMD the ~1500cyc/step barrier+stage overhead of the 4-wave 128^2
// single-phase chassis can't be hidden (m233's structural 72% stall).
// Now: 256x256 tile, 8 waves (2x4), per-wave 128x64 acc[8][4], BK=64 as
// two 32-K half-slots, 128KB LDS (2dbuf x 2half x A,B), gload_lds both
// operands (pre-swizzled source), counted vmcnt(8) once per K-tile,
// setprio around the 64-MFMA cluster. Grid 256 = 32mt x 2nt x splitK4.

typedef __attribute__((ext_vector_type(8))) short short8;
typedef __attribute__((ext_vector_type(4))) float f4;

#define OFF_BT   0u                          // 512x2048 bf16 = 2 MB
#define OFF_W2T  (2u << 20)                  // 128x256 bf16 = 64 KB
#define OFF_PART ((2u << 20) + (64u << 10))  // 64x256 f32 = 64 KB
#define OFF_BIAS ((2u << 20) + (128u << 10)) // 256 f32
#define OFF_P    (4u << 20)                  // 4 x (8192x512) bf16 = 32 MB
#define OFF_XB   (36u << 20)                 // 8192x2048 bf16 = 32 MB

static __device__ __forceinline__ unsigned short f2bf(float f) {
  union { float f; unsigned u; } v; v.f = f;
  return (unsigned short)((v.u + 0x7FFFu + ((v.u >> 16) & 1u)) >> 16);
}
static __device__ __forceinline__ float bf2f(unsigned short h) {
  union { unsigned u; float f; } v; v.u = ((unsigned)h) << 16;
  return v.f;
}
static __device__ __forceinline__ void gload_lds16(const void* g, void* l) {
  __builtin_amdgcn_global_load_lds(
      (const __attribute__((address_space(1))) void*)g,
      (__attribute__((address_space(3))) void*)l, 16, 0, 0);
}

// ---- k_xcvt: X f32 -> Xb bf16 (flat stream, 32 elems/thread) ------------
__global__ __launch_bounds__(256) void k_xcvt(const float* __restrict__ X,
                                              unsigned short* __restrict__ Xb) {
  const size_t t = (size_t)blockIdx.x * 256 + threadIdx.x;
  const float* src = X + t * 32;
  unsigned short* dst = Xb + t * 32;
#pragma unroll
  for (int i = 0; i < 4; ++i) {
    f4 a = *(const f4*)(src + i * 8);
    f4 b = *(const f4*)(src + i * 8 + 4);
    union { short8 s; unsigned u[4]; } pk;
    asm("v_cvt_pk_bf16_f32 %0, %1, %2" : "=v"(pk.u[0]) : "v"(a[0]), "v"(a[1]));
    asm("v_cvt_pk_bf16_f32 %0, %1, %2" : "=v"(pk.u[1]) : "v"(a[2]), "v"(a[3]));
    asm("v_cvt_pk_bf16_f32 %0, %1, %2" : "=v"(pk.u[2]) : "v"(b[0]), "v"(b[1]));
    asm("v_cvt_pk_bf16_f32 %0, %1, %2" : "=v"(pk.u[3]) : "v"(b[2]), "v"(b[3]));
    *(short8*)(dst + i * 8) = pk.s;
  }
}

// ---- k_prep: blocks 0..255: W1 -> Bt (512x2048 bf16, n-major) + bias parts
//              blocks 256..383: W2 (256x128 f32) -> W2t (128x256 bf16, T)
__global__ __launch_bounds__(256) void k_prep(const float* __restrict__ W1,
                                              const float* __restrict__ pos,
                                              const float* __restrict__ W2,
                                              unsigned short* __restrict__ Bt,
                                              unsigned short* __restrict__ W2t,
                                              float* __restrict__ part) {
  __shared__ float T[64][65];
  const int w = blockIdx.x;
  const int t = threadIdx.x;
  if (w >= 256) {
    const int n = w - 256;
    W2t[n * 256 + t] = f2bf(W2[t * 128 + n]);
    return;
  }
  const int h = w >> 7, rem = w & 127, kt = rem >> 2, nt = rem & 3;
  const int krow0 = h * 2048 + kt * 64, col0 = nt * 64;
  const int lr = t >> 2, lc = (t & 3) * 16;
  const float* src = W1 + (size_t)(krow0 + lr) * 256 + col0 + lc;
#pragma unroll
  for (int i = 0; i < 4; ++i) {
    f4 v = *(const f4*)(src + i * 4);
#pragma unroll
    for (int q = 0; q < 4; ++q) T[lr][lc + i * 4 + q] = v[q];
  }
  __syncthreads();
  if (t < 64) {
    float s = 0.f;
#pragma unroll 8
    for (int k = 0; k < 64; ++k) s += T[k][t] * pos[krow0 + k];
    part[(h * 32 + kt) * 256 + col0 + t] = s;
  }
  const int nl = t >> 2, kc = (t & 3) * 16;
  short8 o0, o1;
#pragma unroll
  for (int i = 0; i < 8; ++i) o0[i] = (short)f2bf(T[kc + i][nl]);
#pragma unroll
  for (int i = 0; i < 8; ++i) o1[i] = (short)f2bf(T[kc + 8 + i][nl]);
  unsigned short* dst = Bt + (size_t)(256 * h + col0 + nl) * 2048 + kt * 64 + kc;
  *(short8*)dst = o0;
  *(short8*)(dst + 8) = o1;
}

// ---- k_bias ------------------------------------------------------------
__global__ __launch_bounds__(256) void k_bias(const float* __restrict__ b1,
                                              const float* __restrict__ part,
                                              float* __restrict__ bias) {
  int n = threadIdx.x;
  float s = b1[n];
#pragma unroll 8
  for (int g = 0; g < 64; ++g) s += part[g * 256 + n];
  bias[n] = s;
}

// ---- k_gemm: Ppart[ksp] (8192x512 bf16) = Xb[:,ksp*512:+512] @ Bt^T -----
// 256x256 tile, 512 threads (8 waves 2x4), per-wave 128x64 out (acc[8][4]).
// BK=64 = two 32-K half-slots; LDS = A 4x16KB + B 4x16KB = 128 KB.
// Half-slot layout: 256 rows x 32 bf16 (64B rows), 16B chunk swizzled
// ch ^= (row>>1)&3 (2 lanes/bank = free). DMA pre-swizzles the source.
__global__ __launch_bounds__(512, 2) void k_gemm(const unsigned short* __restrict__ Xb,
                                                 const unsigned short* __restrict__ Bt,
                                                 unsigned short* __restrict__ P) {
  __shared__ __align__(16) char lds[131072];
  const int orig = blockIdx.x;
  const int wgid = (orig & 7) * 32 + (orig >> 3);  // 256 % 8 == 0 -> bijective
  const int mt = wgid >> 3;        // 0..31
  const int nt = (wgid >> 2) & 1;  // 0..1
  const int ksp = wgid & 3;        // 0..3
  const int m0 = mt * 256, n0 = nt * 256, k0 = ksp * 512;
  const int t = threadIdx.x;
  const int wid = t >> 6, lane = t & 63;
  const int wr = wid >> 2, wc = wid & 3;  // wave tile: rows wr*128, cols wc*64

  f4 acc[8][4];
#pragma unroll
  for (int m = 0; m < 8; ++m)
#pragma unroll
    for (int n = 0; n < 4; ++n) acc[m][n] = f4{0.f, 0.f, 0.f, 0.f};

  // DMA one 32-K half (A-half 16KB + B-half 16KB): 4 instr/thread.
#define ISSUE_HALF(BUF, H, KT)                                             \
  do {                                                                     \
    const int kcolb = k0 + (KT) * 64 + (H) * 32;                           \
    _Pragma("unroll") for (int ii = 0; ii < 2; ++ii) {                     \
      const int rl = ii * 128 + wid * 16 + (lane >> 2);                    \
      const int ch = (lane & 3) ^ ((rl >> 1) & 3);                         \
      gload_lds16(Xb + (size_t)(m0 + rl) * 2048 + kcolb + ch * 8,          \
                  &lds[((BUF) * 2 + (H)) * 16384 + ii * 8192 + wid * 1024]);\
      gload_lds16(Bt + (size_t)(n0 + rl) * 2048 + kcolb + ch * 8,          \
                  &lds[65536 + ((BUF) * 2 + (H)) * 16384 + ii * 8192 +     \
                       wid * 1024]);                                       \
    }                                                                      \
  } while (0)

  // 12 ds_read_b128 + 32 MFMA for one 32-K half.
#define COMPUTE_HALF(BUF, H)                                               \
  do {                                                                     \
    const unsigned short* Ab =                                             \
        (const unsigned short*)&lds[((BUF) * 2 + (H)) * 16384];            \
    const unsigned short* Bb =                                             \
        (const unsigned short*)&lds[65536 + ((BUF) * 2 + (H)) * 16384];    \
    short8 af[8], bfv[4];                                                  \
    _Pragma("unroll") for (int m = 0; m < 8; ++m) {                        \
      const int row = wr * 128 + m * 16 + (lane & 15);                     \
      const int ch = (lane >> 4) ^ ((row >> 1) & 3);                       \
      af[m] = *(const short8*)(Ab + row * 32 + ch * 8);                    \
    }                                                                      \
    _Pragma("unroll") for (int n = 0; n < 4; ++n) {                        \
      const int row = wc * 64 + n * 16 + (lane & 15);                      \
      const int ch = (lane >> 4) ^ ((row >> 1) & 3);                       \
      bfv[n] = *(const short8*)(Bb + row * 32 + ch * 8);                   \
    }                                                                      \
    _Pragma("unroll") for (int m = 0; m < 8; ++m)                          \
      _Pragma("unroll") for (int n = 0; n < 4; ++n)                        \
        acc[m][n] = __builtin_amdgcn_mfma_f32_16x16x32_bf16(               \
            af[m], bfv[n], acc[m][n], 0, 0, 0);                            \
  } while (0)

  // prologue: tiles 0,1 fully in flight (16 instr); wait tile 0 (leave 8)
  ISSUE_HALF(0, 0, 0);
  ISSUE_HALF(0, 1, 0);
  ISSUE_HALF(1, 0, 1);
  ISSUE_HALF(1, 1, 1);
  __builtin_amdgcn_sched_barrier(0);
  asm volatile("s_waitcnt vmcnt(8)" ::: "memory");
  __builtin_amdgcn_s_barrier();
  __builtin_amdgcn_sched_barrier(0);

#pragma unroll
  for (int kt = 0; kt < 8; ++kt) {
    const int cur = kt & 1;
    __builtin_amdgcn_s_setprio(1);
    COMPUTE_HALF(cur, 0);
    COMPUTE_HALF(cur, 1);
    __builtin_amdgcn_s_setprio(0);
    __builtin_amdgcn_sched_barrier(0);
    __builtin_amdgcn_s_barrier();  // all waves done reading tile kt
    __builtin_amdgcn_sched_barrier(0);
    if (kt + 2 < 8) {
      ISSUE_HALF(cur, 0, kt + 2);  // overwrite buf cur for tile kt+2
      ISSUE_HALF(cur, 1, kt + 2);
    }
    if (kt < 7) {
      __builtin_amdgcn_sched_barrier(0);
      if (kt + 2 < 8) asm volatile("s_waitcnt vmcnt(8)" ::: "memory");
      else            asm volatile("s_waitcnt vmcnt(0)" ::: "memory");
      __builtin_amdgcn_s_barrier();  // tile kt+1 landed for ALL waves
      __builtin_amdgcn_sched_barrier(0);
    }
  }
#undef ISSUE_HALF
#undef COMPUTE_HALF

  // epilogue: partial write. C/D layout: col=lane&15, row=(lane>>4)*4+reg
  unsigned short* Pp = P + (size_t)ksp * (8192 * 512);
  const int mb = m0 + wr * 128, nb = n0 + wc * 64;
#pragma unroll
  for (int m = 0; m < 8; ++m)
#pragma unroll
    for (int n = 0; n < 4; ++n) {
      const int row0 = mb + m * 16 + ((lane >> 4) << 2);
      const int col = nb + n * 16 + (lane & 15);
#pragma unroll
      for (int r = 0; r < 4; ++r)
        Pp[(size_t)(row0 + r) * 512 + col] = f2bf(acc[m][n][r]);
    }
}

// ---- k_comb: h=gelu(sum_ksp(P0,P1)+bias); out = h@W2 + b2 ---------------
__global__ __launch_bounds__(256) void k_comb(const unsigned short* __restrict__ P,
                                              const unsigned short* __restrict__ W2t,
                                              const float* __restrict__ bias,
                                              const float* __restrict__ b2,
                                              float* __restrict__ out) {
  __shared__ unsigned short W2s[128 * 256];
  __shared__ unsigned short Hs[32 * 256];
  const int wg = blockIdx.x;
  const int b = wg >> 5, jt = wg & 31;
  const int j0 = jt * 32;
  const int t = threadIdx.x;

  {  // stage W2t
    const int row = t >> 1, halfc = (t & 1) * 128;
    const unsigned short* src = W2t + row * 256 + halfc;
    const int cbw = halfc >> 3;
#pragma unroll
    for (int i = 0; i < 16; ++i) {
      short8 v = *(const short8*)(src + i * 8);
      const int c = (cbw + i) ^ (row & 7);
      *(short8*)&W2s[row * 256 + c * 8] = v;
    }
  }
  {  // h rows
    const int r = t >> 3, seg = t & 7;
    const int j = j0 + r;
    const size_t m = (size_t)b * 1024 + j;
    const size_t mp1 = (j < 1023) ? m + 1 : m;
    const float* bs = bias + seg * 32;
    const int cbh = seg * 4;
#pragma unroll
    for (int i = 0; i < 4; ++i) {
      float f0[8];
#pragma unroll
      for (int q = 0; q < 8; ++q) f0[q] = bs[i * 8 + q];
#pragma unroll
      for (int ksp = 0; ksp < 4; ++ksp) {
        const unsigned short* Pk = P + (size_t)ksp * (8192 * 512);
        short8 v0 = *(const short8*)(Pk + m * 512 + seg * 32 + i * 8);
        short8 v1 = *(const short8*)(Pk + mp1 * 512 + 256 + seg * 32 + i * 8);
#pragma unroll
        for (int q = 0; q < 8; ++q)
          f0[q] += bf2f((unsigned short)v0[q]) + bf2f((unsigned short)v1[q]);
      }
      short8 pk;
#pragma unroll
      for (int q = 0; q < 8; ++q) {
        float g = 0.5f * f0[q] * (1.f + erff(f0[q] * 0.70710678118f));
        pk[q] = (short)f2bf(g);
      }
      const int c = (cbh + i) ^ (r & 7);
      *(short8*)&Hs[r * 256 + c * 8] = pk;
    }
  }
  __syncthreads();

  const int wid = t >> 6, lane = t & 63;
  f4 acc[2][2];
#pragma unroll
  for (int i = 0; i < 2; ++i)
#pragma unroll
    for (int j = 0; j < 2; ++j) acc[i][j] = f4{0.f, 0.f, 0.f, 0.f};

#pragma unroll
  for (int ks = 0; ks < 8; ++ks) {
    short8 af[2], bfr[2];
    const int cc = ks * 4 + (lane >> 4);
#pragma unroll
    for (int f = 0; f < 2; ++f) {
      const int ra = f * 16 + (lane & 15);
      af[f] = *(const short8*)&Hs[ra * 256 + ((cc ^ (ra & 7)) << 3)];
      const int rb = wid * 32 + f * 16 + (lane & 15);
      bfr[f] = *(const short8*)&W2s[rb * 256 + ((cc ^ (rb & 7)) << 3)];
    }
#pragma unroll
    for (int i = 0; i < 2; ++i)
#pragma unroll
      for (int j = 0; j < 2; ++j)
        acc[i][j] = __builtin_amdgcn_mfma_f32_16x16x32_bf16(af[i], bfr[j],
                                                            acc[i][j], 0, 0, 0);
  }
#pragma unroll
  for (int i = 0; i < 2; ++i)
#pragma unroll
    for (int j = 0; j < 2; ++j) {
      const int row0 = i * 16 + ((lane >> 4) << 2);
      const int col = wid * 32 + j * 16 + (lane & 15);
      const float bb = b2[col];
#pragma unroll
      for (int r = 0; r < 4; ++r) {
        const int jj = j0 + row0 + r;
        if (jj < 1023)
          out[((size_t)b * 1023 + jj) * 128 + col] = acc[i][j][r] + bb;
      }
    }
}

extern "C" void kernel_launch(void* const* d_in, const int* in_sizes, int n_in,
                              void* d_out, int out_size, void* d_ws, size_t ws_size,
                              hipStream_t stream) {
  const float* x   = (const float*)d_in[0];
  const float* pos = (const float*)d_in[1];
  const float* W1  = (const float*)d_in[2];
  const float* b1  = (const float*)d_in[3];
  const float* W2  = (const float*)d_in[4];
  const float* b2  = (const float*)d_in[5];
  float* out = (float*)d_out;
  char* ws = (char*)d_ws;
  unsigned short* Bt  = (unsigned short*)(ws + OFF_BT);
  unsigned short* W2t = (unsigned short*)(ws + OFF_W2T);
  float* part         = (float*)(ws + OFF_PART);
  float* bias         = (float*)(ws + OFF_BIAS);
  unsigned short* P   = (unsigned short*)(ws + OFF_P);
  unsigned short* Xb  = (unsigned short*)(ws + OFF_XB);

  k_xcvt<<<2048, 256, 0, stream>>>(x, Xb);
  k_prep<<<384, 256, 0, stream>>>(W1, pos, W2, Bt, W2t, part);
  k_bias<<<1, 256, 0, stream>>>(b1, part, bias);
  k_gemm<<<256, 512, 0, stream>>>(Xb, Bt, P);
  k_comb<<<256, 256, 0, stream>>>(P, W2t, bias, b2, out);
}

// Round 9
// 53.913 us; speedup vs baseline: 1.3012x; 1.3012x over previous
//
#include <hip/hip_runtime.h>
#include <hip/hip_bf16.h>
#include <math.h>

// TokenCompressor: B=8, N=16384, C=128, BLOCK=32, STRIDE=16 -> nb=1023
// Decomposition: chunks c of 16 tokens; A = x.view(8192, 2048) (contiguous!)
//   P[m, 0:256]  = chunk[m] @ W1[0:2048]
//   P[m, 256:512]= chunk[m] @ W1[2048:4096]
//   h[j] = gelu(P[j,0:256] + P[j+1,256:512] + b1 + posflat@W1)
//   out[j] = h[j] @ W2 + b2
// R9: kill auxiliary traffic (R8 post-mortem: xcvt 100MB + splitK partials
// 96MB ~ 30us around a 17-GFLOP GEMM). Single-pass GEMM1: A stays f32
// (gload_lds raw, cvt_pk at fragment read), full K=2048 (32 steps, 4x
// better prologue amortization), 128x128 tile x 8 waves, 1 block/CU,
// 2 bufs x (A 32KB f32 + B 16KB bf16) = 96KB, counted vmcnt(6).
// Swizzle fix: A chunk ^= ((row&7)<<1)|((row>>3)&1) -> all 32 banks.

typedef __attribute__((ext_vector_type(8))) short short8;
typedef __attribute__((ext_vector_type(4))) float f4;

#define OFF_BT   0u                          // 512x2048 bf16 = 2 MB
#define OFF_W2T  (2u << 20)                  // 128x256 bf16 = 64 KB
#define OFF_PART ((2u << 20) + (64u << 10))  // 64x256 f32 = 64 KB
#define OFF_BIAS ((2u << 20) + (128u << 10)) // 256 f32
#define OFF_P    (4u << 20)                  // 8192x512 bf16 = 8 MB

static __device__ __forceinline__ unsigned short f2bf(float f) {
  union { float f; unsigned u; } v; v.f = f;
  return (unsigned short)((v.u + 0x7FFFu + ((v.u >> 16) & 1u)) >> 16);
}
static __device__ __forceinline__ float bf2f(unsigned short h) {
  union { unsigned u; float f; } v; v.u = ((unsigned)h) << 16;
  return v.f;
}
static __device__ __forceinline__ void gload_lds16(const void* g, void* l) {
  __builtin_amdgcn_global_load_lds(
      (const __attribute__((address_space(1))) void*)g,
      (__attribute__((address_space(3))) void*)l, 16, 0, 0);
}

// ---- k_prep: blocks 0..255: W1 -> Bt (512x2048 bf16, n-major) + bias parts
//              blocks 256..383: W2 (256x128 f32) -> W2t (128x256 bf16, T)
__global__ __launch_bounds__(256) void k_prep(const float* __restrict__ W1,
                                              const float* __restrict__ pos,
                                              const float* __restrict__ W2,
                                              unsigned short* __restrict__ Bt,
                                              unsigned short* __restrict__ W2t,
                                              float* __restrict__ part) {
  __shared__ float T[64][65];
  const int w = blockIdx.x;
  const int t = threadIdx.x;
  if (w >= 256) {
    const int n = w - 256;
    W2t[n * 256 + t] = f2bf(W2[t * 128 + n]);
    return;
  }
  const int h = w >> 7, rem = w & 127, kt = rem >> 2, nt = rem & 3;
  const int krow0 = h * 2048 + kt * 64, col0 = nt * 64;
  const int lr = t >> 2, lc = (t & 3) * 16;
  const float* src = W1 + (size_t)(krow0 + lr) * 256 + col0 + lc;
#pragma unroll
  for (int i = 0; i < 4; ++i) {
    f4 v = *(const f4*)(src + i * 4);
#pragma unroll
    for (int q = 0; q < 4; ++q) T[lr][lc + i * 4 + q] = v[q];
  }
  __syncthreads();
  if (t < 64) {
    float s = 0.f;
#pragma unroll 8
    for (int k = 0; k < 64; ++k) s += T[k][t] * pos[krow0 + k];
    part[(h * 32 + kt) * 256 + col0 + t] = s;
  }
  const int nl = t >> 2, kc = (t & 3) * 16;
  short8 o0, o1;
#pragma unroll
  for (int i = 0; i < 8; ++i) o0[i] = (short)f2bf(T[kc + i][nl]);
#pragma unroll
  for (int i = 0; i < 8; ++i) o1[i] = (short)f2bf(T[kc + 8 + i][nl]);
  unsigned short* dst = Bt + (size_t)(256 * h + col0 + nl) * 2048 + kt * 64 + kc;
  *(short8*)dst = o0;
  *(short8*)(dst + 8) = o1;
}

// ---- k_bias ------------------------------------------------------------
__global__ __launch_bounds__(256) void k_bias(const float* __restrict__ b1,
                                              const float* __restrict__ part,
                                              float* __restrict__ bias) {
  int n = threadIdx.x;
  float s = b1[n];
#pragma unroll 8
  for (int g = 0; g < 64; ++g) s += part[g * 256 + n];
  bias[n] = s;
}

// ---- k_gemm: P (8192x512 bf16) = X(f32) @ Bt^T, full K=2048 -------------
// 128x128 tile, BK=64, 32 steps. 512 thr = 8 waves (4x2), per-wave 32x64
// (acc[2][4]). 1 block/CU (grid 256). A staged f32 (32KB/buf), B bf16
// (16KB/buf); 2 buffers = 96KB. Counted vmcnt(6): next tile's 6 DMAs stay
// in flight across barriers. f32->bf16 at fragment read (v_cvt_pk_bf16_f32).
__global__ __launch_bounds__(512, 2) void k_gemm(const float* __restrict__ X,
                                                 const unsigned short* __restrict__ Bt,
                                                 unsigned short* __restrict__ P) {
  __shared__ __align__(16) char lds[2][49152];  // A f32 32KB | B bf16 16KB
  const int orig = blockIdx.x;
  const int wgid = (orig & 7) * 32 + (orig >> 3);  // bijective (256%8==0)
  const int mt = wgid >> 2, nt = wgid & 3;  // XCD keeps 8-mt band, all nt
  const int m0 = mt * 128, n0 = nt * 128;
  const int t = threadIdx.x;
  const int wid = t >> 6, lane = t & 63;
  const int wr = wid >> 1, wc = wid & 1;  // wave tile: rows wr*32, cols wc*64

  f4 acc[2][4];
#pragma unroll
  for (int m = 0; m < 2; ++m)
#pragma unroll
    for (int n = 0; n < 4; ++n) acc[m][n] = f4{0.f, 0.f, 0.f, 0.f};

  // 6 gload_lds per thread per tile: 4 A (f32) + 2 B (bf16).
  // A slot s=ii*512+t: row=s>>4, c16=s&15, src chunk = c16 ^ e(row),
  //   e = ((row&7)<<1)|((row>>3)&1) (full 16-chunk spread -> 32 banks).
  // B slot s=ii*512+t: row=s>>3, c8=s&7, src chunk = c8 ^ (row&7).
#define ISSUE(BUF, KT)                                                     \
  do {                                                                     \
    const int kf = (KT) * 64;                                              \
    _Pragma("unroll") for (int ii = 0; ii < 4; ++ii) {                     \
      const int s = ii * 512 + t;                                          \
      const int row = s >> 4, c16 = s & 15;                                \
      const int e = ((row & 7) << 1) | ((row >> 3) & 1);                   \
      gload_lds16(X + (size_t)(m0 + row) * 2048 + kf + ((c16 ^ e) << 2),   \
                  &lds[BUF][ii * 8192 + wid * 1024]);                      \
    }                                                                      \
    _Pragma("unroll") for (int ii = 0; ii < 2; ++ii) {                     \
      const int s = ii * 512 + t;                                          \
      const int row = s >> 3, c8 = s & 7;                                  \
      gload_lds16(Bt + (size_t)(n0 + row) * 2048 + kf +                    \
                      ((c8 ^ (row & 7)) << 3),                             \
                  &lds[BUF][32768 + ii * 8192 + wid * 1024]);              \
    }                                                                      \
  } while (0)

  // per wave per step: 8 A-ds_read_b128 (f32) + 16 cvt_pk + 8 B-ds_read
  // + 16 MFMA (two 32-K slots).
#define COMPUTE(BUF)                                                       \
  do {                                                                     \
    const float* Ab = (const float*)&lds[BUF][0];                          \
    const unsigned short* Bb = (const unsigned short*)&lds[BUF][32768];    \
    _Pragma("unroll") for (int ks = 0; ks < 2; ++ks) {                     \
      short8 af[2];                                                        \
      short8 bfv[4];                                                       \
      _Pragma("unroll") for (int m = 0; m < 2; ++m) {                      \
        const int row = wr * 32 + m * 16 + (lane & 15);                    \
        const int e = ((row & 7) << 1) | ((row >> 3) & 1);                 \
        const int cp = ks * 8 + (lane >> 4) * 2;                           \
        f4 lo = *(const f4*)(Ab + row * 64 + ((cp ^ e) << 2));             \
        f4 hi = *(const f4*)(Ab + row * 64 + (((cp + 1) ^ e) << 2));       \
        union { short8 s8; unsigned u[4]; } pk;                            \
        asm("v_cvt_pk_bf16_f32 %0, %1, %2" : "=v"(pk.u[0])                 \
            : "v"(lo[0]), "v"(lo[1]));                                     \
        asm("v_cvt_pk_bf16_f32 %0, %1, %2" : "=v"(pk.u[1])                 \
            : "v"(lo[2]), "v"(lo[3]));                                     \
        asm("v_cvt_pk_bf16_f32 %0, %1, %2" : "=v"(pk.u[2])                 \
            : "v"(hi[0]), "v"(hi[1]));                                     \
        asm("v_cvt_pk_bf16_f32 %0, %1, %2" : "=v"(pk.u[3])                 \
            : "v"(hi[2]), "v"(hi[3]));                                     \
        af[m] = pk.s8;                                                     \
      }                                                                    \
      _Pragma("unroll") for (int n = 0; n < 4; ++n) {                      \
        const int row = wc * 64 + n * 16 + (lane & 15);                    \
        const int ch = ks * 4 + (lane >> 4);                               \
        bfv[n] = *(const short8*)(Bb + row * 64 +                          \
                                  ((ch ^ (row & 7)) << 3));                \
      }                                                                    \
      __builtin_amdgcn_s_setprio(1);                                       \
      _Pragma("unroll") for (int m = 0; m < 2; ++m)                        \
        _Pragma("unroll") for (int n = 0; n < 4; ++n)                      \
          acc[m][n] = __builtin_amdgcn_mfma_f32_16x16x32_bf16(             \
              af[m], bfv[n], acc[m][n], 0, 0, 0);                          \
      __builtin_amdgcn_s_setprio(0);                                       \
    }                                                                      \
  } while (0)

  // prologue: tiles 0,1 in flight (12 DMAs); wait tile 0 (leave 6)
  ISSUE(0, 0);
  ISSUE(1, 1);
  __builtin_amdgcn_sched_barrier(0);
  asm volatile("s_waitcnt vmcnt(6)" ::: "memory");
  __builtin_amdgcn_s_barrier();
  __builtin_amdgcn_sched_barrier(0);

#pragma unroll 2
  for (int kt = 0; kt < 32; ++kt) {
    COMPUTE(kt & 1);
    __builtin_amdgcn_sched_barrier(0);
    __builtin_amdgcn_s_barrier();  // all waves done reading buf kt&1
    __builtin_amdgcn_sched_barrier(0);
    if (kt < 30) {
      ISSUE(kt & 1, kt + 2);       // 6 new; <=12 in flight
      __builtin_amdgcn_sched_barrier(0);
      asm volatile("s_waitcnt vmcnt(6)" ::: "memory");  // tile kt+1 landed
      __builtin_amdgcn_s_barrier();
      __builtin_amdgcn_sched_barrier(0);
    } else if (kt == 30) {
      asm volatile("s_waitcnt vmcnt(0)" ::: "memory");  // tile 31 landed
      __builtin_amdgcn_s_barrier();
      __builtin_amdgcn_sched_barrier(0);
    }
  }
#undef ISSUE
#undef COMPUTE

  // epilogue: P bf16. C/D layout: col=lane&15, row=(lane>>4)*4+reg
  const int mb = m0 + wr * 32, nb = n0 + wc * 64;
#pragma unroll
  for (int m = 0; m < 2; ++m)
#pragma unroll
    for (int n = 0; n < 4; ++n) {
      const int row0 = mb + m * 16 + ((lane >> 4) << 2);
      const int col = nb + n * 16 + (lane & 15);
#pragma unroll
      for (int r = 0; r < 4; ++r)
        P[(size_t)(row0 + r) * 512 + col] = f2bf(acc[m][n][r]);
    }
}

// ---- k_comb: h=gelu(P0+P1+bias); out = h@W2 + b2 -----------------------
__global__ __launch_bounds__(256) void k_comb(const unsigned short* __restrict__ P,
                                              const unsigned short* __restrict__ W2t,
                                              const float* __restrict__ bias,
                                              const float* __restrict__ b2,
                                              float* __restrict__ out) {
  __shared__ unsigned short W2s[128 * 256];
  __shared__ unsigned short Hs[32 * 256];
  const int wg = blockIdx.x;
  const int b = wg >> 5, jt = wg & 31;
  const int j0 = jt * 32;
  const int t = threadIdx.x;

  {  // stage W2t (rows 512B; swizzle slot ^= row&7)
    const int row = t >> 1, halfc = (t & 1) * 128;
    const unsigned short* src = W2t + row * 256 + halfc;
    const int cbw = halfc >> 3;
#pragma unroll
    for (int i = 0; i < 16; ++i) {
      short8 v = *(const short8*)(src + i * 8);
      const int c = (cbw + i) ^ (row & 7);
      *(short8*)&W2s[row * 256 + c * 8] = v;
    }
  }
  {  // h rows: thread = (row r, 32-col segment)
    const int r = t >> 3, seg = t & 7;
    const int j = j0 + r;
    const size_t m = (size_t)b * 1024 + j;
    const size_t mp1 = (j < 1023) ? m + 1 : m;  // clamp (masked later)
    const unsigned short* p0 = P + m * 512 + seg * 32;
    const unsigned short* p1 = P + mp1 * 512 + 256 + seg * 32;
    const float* bs = bias + seg * 32;
    const int cbh = seg * 4;
#pragma unroll
    for (int i = 0; i < 4; ++i) {
      short8 v0 = *(const short8*)(p0 + i * 8);
      short8 v1 = *(const short8*)(p1 + i * 8);
      short8 pk;
#pragma unroll
      for (int q = 0; q < 8; ++q) {
        float f = bf2f((unsigned short)v0[q]) + bf2f((unsigned short)v1[q]) +
                  bs[i * 8 + q];
        float g = 0.5f * f * (1.f + erff(f * 0.70710678118f));
        pk[q] = (short)f2bf(g);
      }
      const int c = (cbh + i) ^ (r & 7);
      *(short8*)&Hs[r * 256 + c * 8] = pk;
    }
  }
  __syncthreads();

  const int wid = t >> 6, lane = t & 63;
  f4 acc[2][2];
#pragma unroll
  for (int i = 0; i < 2; ++i)
#pragma unroll
    for (int j = 0; j < 2; ++j) acc[i][j] = f4{0.f, 0.f, 0.f, 0.f};

#pragma unroll
  for (int ks = 0; ks < 8; ++ks) {
    short8 af[2], bfr[2];
    const int cc = ks * 4 + (lane >> 4);
#pragma unroll
    for (int f = 0; f < 2; ++f) {
      const int ra = f * 16 + (lane & 15);
      af[f] = *(const short8*)&Hs[ra * 256 + ((cc ^ (ra & 7)) << 3)];
      const int rb = wid * 32 + f * 16 + (lane & 15);
      bfr[f] = *(const short8*)&W2s[rb * 256 + ((cc ^ (rb & 7)) << 3)];
    }
#pragma unroll
    for (int i = 0; i < 2; ++i)
#pragma unroll
      for (int j = 0; j < 2; ++j)
        acc[i][j] = __builtin_amdgcn_mfma_f32_16x16x32_bf16(af[i], bfr[j],
                                                            acc[i][j], 0, 0, 0);
  }
#pragma unroll
  for (int i = 0; i < 2; ++i)
#pragma unroll
    for (int j = 0; j < 2; ++j) {
      const int row0 = i * 16 + ((lane >> 4) << 2);
      const int col = wid * 32 + j * 16 + (lane & 15);
      const float bb = b2[col];
#pragma unroll
      for (int r = 0; r < 4; ++r) {
        const int jj = j0 + row0 + r;
        if (jj < 1023)
          out[((size_t)b * 1023 + jj) * 128 + col] = acc[i][j][r] + bb;
      }
    }
}

extern "C" void kernel_launch(void* const* d_in, const int* in_sizes, int n_in,
                              void* d_out, int out_size, void* d_ws, size_t ws_size,
                              hipStream_t stream) {
  const float* x   = (const float*)d_in[0];
  const float* pos = (const float*)d_in[1];
  const float* W1  = (const float*)d_in[2];
  const float* b1  = (const float*)d_in[3];
  const float* W2  = (const float*)d_in[4];
  const float* b2  = (const float*)d_in[5];
  float* out = (float*)d_out;
  char* ws = (char*)d_ws;
  unsigned short* Bt  = (unsigned short*)(ws + OFF_BT);
  unsigned short* W2t = (unsigned short*)(ws + OFF_W2T);
  float* part         = (float*)(ws + OFF_PART);
  float* bias         = (float*)(ws + OFF_BIAS);
  unsigned short* P   = (unsigned short*)(ws + OFF_P);

  k_prep<<<384, 256, 0, stream>>>(W1, pos, W2, Bt, W2t, part);
  k_bias<<<1, 256, 0, stream>>>(b1, part, bias);
  k_gemm<<<256, 512, 0, stream>>>(x, Bt, P);
  k_comb<<<256, 256, 0, stream>>>(P, W2t, bias, b2, out);
}